// Round 1
// baseline (884.537 us; speedup 1.0000x reference)
//
#include <hip/hip_runtime.h>

#define SAT_ELEMS (32*64*64*64)        // 8388608 elements per input
#define PER_I (64*64*64)               // 262144 elements per batch item
#define DIST_OFF (2*SAT_ELEMS)         // 16777216
#define ORIEN_OFF (DIST_OFF + 32*32)   // 16778240

// ---------------- copy inputs to outputs 0/1 ----------------
__global__ __launch_bounds__(256) void copy_kernel(const float4* __restrict__ sat,
                                                   const float4* __restrict__ grd,
                                                   float4* __restrict__ out) {
  const int n4 = SAT_ELEMS / 4;
  int idx = blockIdx.x * 256 + threadIdx.x;
  int stride = gridDim.x * 256;
  for (int t = idx; t < n4; t += stride) out[t] = sat[t];
  for (int t = idx; t < n4; t += stride) out[n4 + t] = grd[t];
}

// ---------------- per-i norms: sqrt(sum(sat[i]^2) + 1e-8) ----------------
__global__ __launch_bounds__(256) void norm_kernel(const float4* __restrict__ sat,
                                                   float* __restrict__ norms) {
  int i = blockIdx.x;
  const float4* p = sat + (size_t)i * (PER_I / 4);
  float s = 0.f;
  for (int t = threadIdx.x; t < PER_I / 4; t += 256) {
    float4 v = p[t];
    s += v.x * v.x + v.y * v.y + v.z * v.z + v.w * v.w;
  }
  for (int off = 32; off; off >>= 1) s += __shfl_down(s, off, 64);
  __shared__ float red[4];
  int lane = threadIdx.x & 63, wv = threadIdx.x >> 6;
  if (lane == 0) red[wv] = s;
  __syncthreads();
  if (threadIdx.x == 0) norms[i] = sqrtf(red[0] + red[1] + red[2] + red[3] + 1e-8f);
}

// ---------------- Gram GEMM over rows + diagonal reduce + argmax ----------------
// C[(i*64+hs), (j*64+hg)] = sum_{c,w} sat[i,c,hs,w] * grd[j,c,hg,63-w]
// corr[i,j,y] = sum over (hs-hg) == y (mod 64);  orien[i,j] = argmax_y corr (first max)
#define BK 32

__global__ __launch_bounds__(256) void gram1_kernel(const float* __restrict__ sat,
                                                    const float* __restrict__ grd,
                                                    float* __restrict__ out,
                                                    int* __restrict__ orien_ws) {
  __shared__ float As[BK][128];
  __shared__ float Bs[BK][128];
  __shared__ float corr_s[2][2][64];

  const int bx = blockIdx.x;   // i-pair block: i = 2*bx + {0,1}
  const int by = blockIdx.y;   // j-pair block: j = 2*by + {0,1}
  const int tid = threadIdx.x;
  const int lane = tid & 63;
  const int wv = tid >> 6;               // wave 0..3 -> quadrant
  const int qm = wv >> 1, qn = wv & 1;   // each wave owns one (i,j) pair's 64x64 tile
  const int tx = lane & 7;               // n within quadrant (8 floats)
  const int ty = lane >> 3;              // m within quadrant (8 floats)
  const int m0 = qm * 64 + ty * 8;
  const int n0 = qn * 64 + tx * 8;

  float acc[8][8];
  #pragma unroll
  for (int a = 0; a < 8; ++a)
    #pragma unroll
    for (int b = 0; b < 8; ++b) acc[a][b] = 0.f;

  const int r0 = tid >> 3;   // staging row (+32 per q)
  const int pos = tid & 7;   // staging 4-float chunk within BK

  for (int kt = 0; kt < 4096; kt += BK) {
    const int c = kt >> 6;         // channel
    const int w0 = kt & 63;        // 0 or 32
    #pragma unroll
    for (int q = 0; q < 4; ++q) {
      int r = r0 + 32 * q;                     // 0..127
      int sub = r >> 6, rr = r & 63;
      // A[m=r][k=w0+pos*4 .. +3] = sat[i, c, hs=rr, w]
      const float* srcA = sat + ((((2 * bx + sub) * 64 + c) * 64 + rr) * 64 + w0 + pos * 4);
      float4 va = *(const float4*)srcA;
      As[pos * 4 + 0][r] = va.x; As[pos * 4 + 1][r] = va.y;
      As[pos * 4 + 2][r] = va.z; As[pos * 4 + 3][r] = va.w;
      // B[n=r][k=w0+ww] = grd[j, c, hg=rr, 63-w0-ww]  (reversed width)
      const float* srcB = grd + ((((2 * by + sub) * 64 + c) * 64 + rr) * 64 + (63 - w0 - pos * 4));
      Bs[pos * 4 + 0][r] = srcB[0];  Bs[pos * 4 + 1][r] = srcB[-1];
      Bs[pos * 4 + 2][r] = srcB[-2]; Bs[pos * 4 + 3][r] = srcB[-3];
    }
    __syncthreads();
    #pragma unroll 8
    for (int k = 0; k < BK; ++k) {
      float a[8], b[8];
      *(float4*)&a[0] = *(const float4*)&As[k][m0];
      *(float4*)&a[4] = *(const float4*)&As[k][m0 + 4];
      *(float4*)&b[0] = *(const float4*)&Bs[k][n0];
      *(float4*)&b[4] = *(const float4*)&Bs[k][n0 + 4];
      #pragma unroll
      for (int mm = 0; mm < 8; ++mm)
        #pragma unroll
        for (int nn = 0; nn < 8; ++nn)
          acc[mm][nn] = fmaf(a[mm], b[nn], acc[mm][nn]);
    }
    __syncthreads();
  }

  // ---- epilogue: fold 64x64 per-pair tile into corr[y], y=(hs-hg) mod 64 ----
  ((float*)corr_s)[tid] = 0.f;
  __syncthreads();
  float part[15];
  #pragma unroll
  for (int d = 0; d < 15; ++d) part[d] = 0.f;
  #pragma unroll
  for (int mm = 0; mm < 8; ++mm)
    #pragma unroll
    for (int nn = 0; nn < 8; ++nn)
      part[mm - nn + 7] += acc[mm][nn];
  const int g8 = (ty - tx) * 8;
  #pragma unroll
  for (int d = 0; d < 15; ++d) {
    int y = (g8 + d - 7) & 63;
    atomicAdd(&corr_s[qm][qn][y], part[d]);
  }
  __syncthreads();
  // first-index argmax per pair (matches jnp.argmax tie-break)
  if (lane == 0) {
    float best = corr_s[qm][qn][0];
    int besty = 0;
    for (int y = 1; y < 64; ++y) {
      float v = corr_s[qm][qn][y];
      if (v > best) { best = v; besty = y; }
    }
    int i = 2 * bx + qm, j = 2 * by + qn;
    out[ORIEN_OFF + i * 32 + j] = (float)besty;
    orien_ws[i * 32 + j] = besty;
  }
}

// ---------------- per-pair dot at shift o=orien[i,j] -> distance ----------------
__global__ __launch_bounds__(256) void dot_kernel(const float* __restrict__ sat,
                                                  const float* __restrict__ grd,
                                                  const float* __restrict__ norms,
                                                  const int* __restrict__ orien_ws,
                                                  float* __restrict__ out) {
  const int bx = blockIdx.x;
  const int i = bx >> 5, j = bx & 31;   // consecutive blocks share i -> sat[i] L2-hot
  const int o = orien_ws[i * 32 + j];
  const int tid = threadIdx.x;
  const int lane = tid & 63, wv = tid >> 6;
  const float* satb = sat + i * PER_I;
  const float* grdb = grd + j * PER_I;
  const int ks = (lane + o) & 63;
  float s = 0.f;
  #pragma unroll 4
  for (int r = wv; r < 4096; r += 4) {
    s = fmaf(satb[r * 64 + ks], grdb[r * 64 + lane], s);
  }
  for (int off = 32; off; off >>= 1) s += __shfl_down(s, off, 64);
  __shared__ float red[4];
  if (lane == 0) red[wv] = s;
  __syncthreads();
  if (tid == 0) {
    float dot = (red[0] + red[1] + red[2] + red[3]) / norms[i];
    out[DIST_OFF + j * 32 + i] = 2.f - 2.f * dot;
  }
}

extern "C" void kernel_launch(void* const* d_in, const int* in_sizes, int n_in,
                              void* d_out, int out_size, void* d_ws, size_t ws_size,
                              hipStream_t stream) {
  const float* sat = (const float*)d_in[0];
  const float* grd = (const float*)d_in[1];
  float* out = (float*)d_out;
  float* norms = (float*)d_ws;
  int* orien_ws = (int*)((float*)d_ws + 32);

  copy_kernel<<<2048, 256, 0, stream>>>((const float4*)sat, (const float4*)grd, (float4*)out);
  norm_kernel<<<32, 256, 0, stream>>>((const float4*)sat, norms);
  gram1_kernel<<<dim3(16, 16), 256, 0, stream>>>(sat, grd, out, orien_ws);
  dot_kernel<<<1024, 256, 0, stream>>>(sat, grd, norms, orien_ws, out);
}

// Round 2
// 774.626 us; speedup vs baseline: 1.1419x; 1.1419x over previous
//
#include <hip/hip_runtime.h>

typedef _Float16 f16;
typedef _Float16 f16x8 __attribute__((ext_vector_type(8)));
typedef float f32x16 __attribute__((ext_vector_type(16)));

#define SAT_ELEMS (32*64*64*64)
#define PER_I (64*64*64)
#define DIST_OFF (2*SAT_ELEMS)
#define ORIEN_OFF (DIST_OFF + 32*32)

// ws layout (float units)
#define WS_NORMS 0          // float[32]
#define WS_ORIEN 64         // int[1024]
#define WS_CORR  2048       // float[1024*64]
#define WS_DOTS  67584      // float[1024]

// ---------------- zero corr+dots scratch ----------------
__global__ __launch_bounds__(256) void zero_kernel(float* __restrict__ ws) {
  int t = blockIdx.x * 256 + threadIdx.x;
  if (t < 65536 + 1024) ws[WS_CORR + t] = 0.f;
}

// ---------------- copy inputs to outputs 0/1 ----------------
__global__ __launch_bounds__(256) void copy_kernel(const float4* __restrict__ sat,
                                                   const float4* __restrict__ grd,
                                                   float4* __restrict__ out) {
  const int n4 = SAT_ELEMS / 4;
  int idx = blockIdx.x * 256 + threadIdx.x;
  int stride = gridDim.x * 256;
  for (int t = idx; t < n4; t += stride) out[t] = sat[t];
  for (int t = idx; t < n4; t += stride) out[n4 + t] = grd[t];
}

// ---------------- per-i norms ----------------
__global__ __launch_bounds__(256) void norm_kernel(const float4* __restrict__ sat,
                                                   float* __restrict__ norms) {
  int i = blockIdx.x;
  const float4* p = sat + (size_t)i * (PER_I / 4);
  float s = 0.f;
  for (int t = threadIdx.x; t < PER_I / 4; t += 256) {
    float4 v = p[t];
    s += v.x * v.x + v.y * v.y + v.z * v.z + v.w * v.w;
  }
  for (int off = 32; off; off >>= 1) s += __shfl_down(s, off, 64);
  __shared__ float red[4];
  int lane = threadIdx.x & 63, wv = threadIdx.x >> 6;
  if (lane == 0) red[wv] = s;
  __syncthreads();
  if (threadIdx.x == 0) norms[i] = sqrtf(red[0] + red[1] + red[2] + red[3] + 1e-8f);
}

// ---------------- MFMA Gram + diagonal fold (partial over K) ----------------
// Per block: 2x2 pairs (i,j), K-slice of 1024. 4 waves, wave = one pair.
// 3-pass f16 split precision: ah*bh + ah*bl + al*bh.
__global__ __launch_bounds__(256, 3) void gram2_kernel(const float* __restrict__ sat,
                                                       const float* __restrict__ grd,
                                                       float* __restrict__ ws) {
  // LDS: rows of 64 f16 = 128B = 8 x 16B chunks; chunks 0..3 = hi(k0..31), 4..7 = lo.
  // chunk stored at physical position (c ^ (row&7)) -> conflict-minimal b128 r/w.
  __shared__ f16 As[2][64][64];
  __shared__ f16 Bs[2][64][64];
  __shared__ float corr_s[4][64];

  // XCD-chunked swizzle on x (256 blocks, 32 per XCD)
  int flat = blockIdx.x;
  int wg = (flat & 7) * 32 + (flat >> 3);
  const int bxi = wg >> 4, bxj = wg & 15;
  const int kz = blockIdx.y;      // 0..3 K-slices of 1024

  const int tid = threadIdx.x;
  const int lane = tid & 63;
  const int wv = tid >> 6;

  // ---- staging role: one row of one matrix per thread ----
  const int srow = lane;
  const bool isB = wv >= 2;
  const int idx_m = isB ? (2 * bxj + (wv & 1)) : (2 * bxi + (wv & 1));
  const float* srcbase = (isB ? grd : sat) + (size_t)idx_m * PER_I + (size_t)srow * 64;
  f16* dstrow = isB ? &Bs[wv - 2][srow][0] : &As[wv & 1][srow][0];
  const int rx = srow & 7;

  // ---- MFMA role ----
  const int iq = wv >> 1, jq = wv & 1;
  const int lr = lane & 31, lh = lane >> 5;
  const f16* arow0 = &As[iq][0][0];
  const f16* brow0 = &Bs[jq][0][0];

  f32x16 acc[2][2];
  #pragma unroll
  for (int mh = 0; mh < 2; ++mh)
    #pragma unroll
    for (int nh = 0; nh < 2; ++nh)
      #pragma unroll
      for (int q = 0; q < 16; ++q) acc[mh][nh][q] = 0.f;

  const int k0base = kz * 1024;
  for (int s = 0; s < 32; ++s) {
    const int k0 = k0base + s * 32;
    const int c = k0 >> 6;         // channel
    const int w0 = k0 & 63;        // 0 or 32
    // ---- stage 32 k-values (hi+lo) for this thread's row ----
    {
      const float* src = srcbase + (size_t)c * 4096;
      #pragma unroll
      for (int cq = 0; cq < 4; ++cq) {
        f16x8 h, l;
        #pragma unroll
        for (int half = 0; half < 2; ++half) {
          const int q = cq * 2 + half;
          if (!isB) {
            float4 v = *(const float4*)(src + w0 + q * 4);
            const float xs[4] = {v.x, v.y, v.z, v.w};
            #pragma unroll
            for (int e = 0; e < 4; ++e) {
              f16 hh = (f16)xs[e];
              h[half * 4 + e] = hh;
              l[half * 4 + e] = (f16)(xs[e] - (float)hh);
            }
          } else {
            // element t=q*4+e is grd[...][63-w0-t] -> reversed float4
            float4 v = *(const float4*)(src + 60 - w0 - q * 4);
            const float xs[4] = {v.w, v.z, v.y, v.x};
            #pragma unroll
            for (int e = 0; e < 4; ++e) {
              f16 hh = (f16)xs[e];
              h[half * 4 + e] = hh;
              l[half * 4 + e] = (f16)(xs[e] - (float)hh);
            }
          }
        }
        *(f16x8*)(dstrow + ((cq ^ rx) * 8)) = h;
        *(f16x8*)(dstrow + (((cq + 4) ^ rx) * 8)) = l;
      }
    }
    __syncthreads();
    // ---- compute: 2 x (k=16) steps, 12 MFMA each ----
    #pragma unroll
    for (int kk = 0; kk < 2; ++kk) {
      f16x8 ah[2], al[2], bh[2], bl[2];
      const int c0 = kk * 2 + lh;
      #pragma unroll
      for (int mh = 0; mh < 2; ++mh) {
        const int row = mh * 32 + lr;
        const int rk = row & 7;
        ah[mh] = *(const f16x8*)(arow0 + row * 64 + ((c0 ^ rk) * 8));
        al[mh] = *(const f16x8*)(arow0 + row * 64 + (((c0 + 4) ^ rk) * 8));
        bh[mh] = *(const f16x8*)(brow0 + row * 64 + ((c0 ^ rk) * 8));
        bl[mh] = *(const f16x8*)(brow0 + row * 64 + (((c0 + 4) ^ rk) * 8));
      }
      #pragma unroll
      for (int mh = 0; mh < 2; ++mh)
        #pragma unroll
        for (int nh = 0; nh < 2; ++nh) {
          acc[mh][nh] = __builtin_amdgcn_mfma_f32_32x32x16_f16(ah[mh], bh[nh], acc[mh][nh], 0, 0, 0);
          acc[mh][nh] = __builtin_amdgcn_mfma_f32_32x32x16_f16(ah[mh], bl[nh], acc[mh][nh], 0, 0, 0);
          acc[mh][nh] = __builtin_amdgcn_mfma_f32_32x32x16_f16(al[mh], bh[nh], acc[mh][nh], 0, 0, 0);
        }
    }
    __syncthreads();
  }

  // ---- fold 64x64 pair tile into corr[y], y = (hs-hg) mod 64 ----
  ((float*)corr_s)[tid] = 0.f;
  __syncthreads();
  #pragma unroll
  for (int r = 0; r < 16; ++r) {
    const int rowof = (r & 3) + 8 * (r >> 2);
    const int y0 = (rowof + 4 * lh - lr) & 63;      // mh==nh
    const int y1 = (y0 + 32) & 63;                  // mh!=nh
    atomicAdd(&corr_s[wv][y0], acc[0][0][r] + acc[1][1][r]);
    atomicAdd(&corr_s[wv][y1], acc[0][1][r] + acc[1][0][r]);
  }
  __syncthreads();
  {
    const int p = tid >> 6, y = tid & 63;
    const int ip = 2 * bxi + (p >> 1), jp = 2 * bxj + (p & 1);
    atomicAdd(&ws[WS_CORR + ((size_t)ip * 32 + jp) * 64 + y], corr_s[p][y]);
  }
}

// ---------------- argmax over corr -> orien ----------------
__global__ __launch_bounds__(256) void argmax_kernel(const float* __restrict__ ws,
                                                     float* __restrict__ out,
                                                     int* __restrict__ orien) {
  int p = blockIdx.x * 256 + threadIdx.x;
  if (p >= 1024) return;
  const float* c = ws + WS_CORR + (size_t)p * 64;
  float best = c[0];
  int by = 0;
  for (int y = 1; y < 64; ++y) {
    float v = c[y];
    if (v > best) { best = v; by = y; }
  }
  orien[p] = by;
  out[ORIEN_OFF + p] = (float)by;
}

// ---------------- per-pair width-shifted dot (tiled 4i x 8j x 16 k-slices) ----------------
__global__ __launch_bounds__(512) void dot2_kernel(const float* __restrict__ sat,
                                                   const float* __restrict__ grd,
                                                   const int* __restrict__ orien,
                                                   float* __restrict__ dots) {
  const int bi = blockIdx.x;   // 0..7  -> 4 i's
  const int bj = blockIdx.y;   // 0..3  -> 8 j's
  const int bz = blockIdx.z;   // 0..15 -> 256 k-rows
  const int tid = threadIdx.x, lane = tid & 63, wv = tid >> 6;
  const int j = bj * 8 + wv;
  const int r0 = bz * 256;
  const float* gp = grd + (size_t)j * PER_I + (size_t)r0 * 64 + lane;
  const float* sp0; const float* sp1; const float* sp2; const float* sp3;
  {
    int i0 = bi * 4;
    sp0 = sat + (size_t)(i0 + 0) * PER_I + (size_t)r0 * 64 + ((lane + orien[(i0 + 0) * 32 + j]) & 63);
    sp1 = sat + (size_t)(i0 + 1) * PER_I + (size_t)r0 * 64 + ((lane + orien[(i0 + 1) * 32 + j]) & 63);
    sp2 = sat + (size_t)(i0 + 2) * PER_I + (size_t)r0 * 64 + ((lane + orien[(i0 + 2) * 32 + j]) & 63);
    sp3 = sat + (size_t)(i0 + 3) * PER_I + (size_t)r0 * 64 + ((lane + orien[(i0 + 3) * 32 + j]) & 63);
  }
  float a0 = 0.f, a1 = 0.f, a2 = 0.f, a3 = 0.f;
  #pragma unroll 4
  for (int r = 0; r < 256; ++r) {
    float g = gp[(size_t)r * 64];
    a0 = fmaf(sp0[(size_t)r * 64], g, a0);
    a1 = fmaf(sp1[(size_t)r * 64], g, a1);
    a2 = fmaf(sp2[(size_t)r * 64], g, a2);
    a3 = fmaf(sp3[(size_t)r * 64], g, a3);
  }
  float av[4] = {a0, a1, a2, a3};
  #pragma unroll
  for (int ii = 0; ii < 4; ++ii) {
    float s = av[ii];
    for (int off = 32; off; off >>= 1) s += __shfl_down(s, off, 64);
    if (lane == 0) atomicAdd(&dots[(bi * 4 + ii) * 32 + j], s);
  }
}

// ---------------- finalize distance ----------------
__global__ __launch_bounds__(256) void finalize_kernel(const float* __restrict__ ws,
                                                       float* __restrict__ out) {
  int t = blockIdx.x * 256 + threadIdx.x;
  if (t >= 1024) return;
  int jj = t >> 5, ii = t & 31;
  float dot = ws[WS_DOTS + ii * 32 + jj] / ws[WS_NORMS + ii];
  out[DIST_OFF + jj * 32 + ii] = 2.f - 2.f * dot;
}

extern "C" void kernel_launch(void* const* d_in, const int* in_sizes, int n_in,
                              void* d_out, int out_size, void* d_ws, size_t ws_size,
                              hipStream_t stream) {
  const float* sat = (const float*)d_in[0];
  const float* grd = (const float*)d_in[1];
  float* out = (float*)d_out;
  float* wsf = (float*)d_ws;

  zero_kernel<<<260, 256, 0, stream>>>(wsf);
  copy_kernel<<<2048, 256, 0, stream>>>((const float4*)sat, (const float4*)grd, (float4*)out);
  norm_kernel<<<32, 256, 0, stream>>>((const float4*)sat, wsf + WS_NORMS);
  gram2_kernel<<<dim3(256, 4), 256, 0, stream>>>(sat, grd, wsf);
  argmax_kernel<<<4, 256, 0, stream>>>(wsf, out, (int*)(wsf + WS_ORIEN));
  dot2_kernel<<<dim3(8, 4, 16), 512, 0, stream>>>(sat, grd, (const int*)(wsf + WS_ORIEN), wsf + WS_DOTS);
  finalize_kernel<<<4, 256, 0, stream>>>(wsf, out);
}

// Round 4
// 409.919 us; speedup vs baseline: 2.1578x; 1.8897x over previous
//
#include <hip/hip_runtime.h>

typedef _Float16 f16;
typedef _Float16 f16x8 __attribute__((ext_vector_type(8)));
typedef float f32x16 __attribute__((ext_vector_type(16)));

#define SAT_ELEMS (32*64*64*64)
#define PER_I (64*64*64)
#define DIST_OFF (2*SAT_ELEMS)
#define ORIEN_OFF (DIST_OFF + 32*32)

// ws layout (float units)
#define WS_NORMS 0          // float[32]
#define WS_ORIEN 64         // int[1024]
#define WS_CORR  2048       // float[1024*64]
#define WS_DOTS  67584      // float[1024]

// ---------------- zero corr+dots scratch ----------------
__global__ __launch_bounds__(256) void zero_kernel(float* __restrict__ ws) {
  int t = blockIdx.x * 256 + threadIdx.x;
  if (t < 65536 + 1024) ws[WS_CORR + t] = 0.f;
}

// ---------------- copy inputs to outputs 0/1 ----------------
__global__ __launch_bounds__(256) void copy_kernel(const float4* __restrict__ sat,
                                                   const float4* __restrict__ grd,
                                                   float4* __restrict__ out) {
  const int n4 = SAT_ELEMS / 4;
  int idx = blockIdx.x * 256 + threadIdx.x;
  int stride = gridDim.x * 256;
  for (int t = idx; t < n4; t += stride) out[t] = sat[t];
  for (int t = idx; t < n4; t += stride) out[n4 + t] = grd[t];
}

// ---------------- per-i norms ----------------
__global__ __launch_bounds__(256) void norm_kernel(const float4* __restrict__ sat,
                                                   float* __restrict__ norms) {
  int i = blockIdx.x;
  const float4* p = sat + (size_t)i * (PER_I / 4);
  float s = 0.f;
  for (int t = threadIdx.x; t < PER_I / 4; t += 256) {
    float4 v = p[t];
    s += v.x * v.x + v.y * v.y + v.z * v.z + v.w * v.w;
  }
  for (int off = 32; off; off >>= 1) s += __shfl_down(s, off, 64);
  __shared__ float red[4];
  int lane = threadIdx.x & 63, wv = threadIdx.x >> 6;
  if (lane == 0) red[wv] = s;
  __syncthreads();
  if (threadIdx.x == 0) norms[i] = sqrtf(red[0] + red[1] + red[2] + red[3] + 1e-8f);
}

// ---------------- MFMA Gram, pipelined (tile 256x128, K-slice 1024) ----------------
// 8 waves; wave (wr,wc) owns pair (i = ipg*4+wr, j = jpg*2+wc) -> 64x64 tile.
// 3-pass f16 split precision: ah*bh + ah*bl + al*bh  (identical numerics to r2).
__global__ __launch_bounds__(512) void gram3_kernel(const float* __restrict__ sat,
                                                    const float* __restrict__ grd,
                                                    float* __restrict__ ws) {
  __shared__ f16 As[2][256][64];   // 64KB: row = 128B = 8x16B chunks, 0-3 hi, 4-7 lo, phys = ck^(r&7)
  __shared__ f16 Bs[2][128][64];   // 32KB
  __shared__ float corr_s[8][64];  // 2KB

  // XCD-chunked swizzle: XCD x <- ipg x; within: jpg outer, kz inner
  const int bid = blockIdx.x;
  const int ipg = bid & 7;         // 0..7   (4 i's each)
  const int rem = bid >> 3;        // 0..63
  const int jpg = rem >> 2;        // 0..15  (2 j's each)
  const int kz  = rem & 3;         // K-slice of 1024

  const int tid = threadIdx.x;
  const int lane = tid & 63;
  const int wv = tid >> 6;
  const int wr = wv >> 1, wc = wv & 1;
  const int lr = lane & 31, lh = lane >> 5;

  // staging roles: thread -> (A row, k-half); threads <256 also (B row, k-half)
  const int ra = tid >> 1, ua = tid & 1;
  const int ia = ipg * 4 + (ra >> 6), ha = ra & 63;
  const bool hasB = (tid < 256);
  const int rb = (tid >> 1) & 127, ub = tid & 1;
  const int jb = jpg * 2 + (rb >> 6), hb = rb & 63;

  const float* abase = sat + (size_t)ia * PER_I + (size_t)ha * 64;
  const float* bbase = grd + (size_t)jb * PER_I + (size_t)hb * 64;

  f32x16 acc[2][2];
  #pragma unroll
  for (int mh = 0; mh < 2; ++mh)
    #pragma unroll
    for (int nh = 0; nh < 2; ++nh)
      #pragma unroll
      for (int q = 0; q < 16; ++q) acc[mh][nh][q] = 0.f;

  float4 avA[4], avB[4];

  auto LOADA = [&](int S) {
    const int c = S >> 1, w0 = (S & 1) * 32;
    const float* p = abase + (size_t)c * 4096 + w0 + ua * 16;
    #pragma unroll
    for (int q = 0; q < 4; ++q) avA[q] = *(const float4*)(p + q * 4);
  };
  auto LOADB = [&](int S) {
    const int c = S >> 1, w0 = (S & 1) * 32;
    const float* p = bbase + (size_t)c * 4096;
    #pragma unroll
    for (int q = 0; q < 4; ++q) avB[q] = *(const float4*)(p + 60 - w0 - ub * 16 - q * 4);
  };
  auto WRITEA = [&](int buf) {
    f16* row = &As[buf][ra][0];
    const int rx = ra & 7;
    #pragma unroll
    for (int half = 0; half < 2; ++half) {
      f16x8 h, l;
      #pragma unroll
      for (int q = 0; q < 2; ++q) {
        float4 v = avA[half * 2 + q];
        const float xs[4] = {v.x, v.y, v.z, v.w};
        #pragma unroll
        for (int e = 0; e < 4; ++e) {
          f16 hh = (f16)xs[e];
          h[q * 4 + e] = hh;
          l[q * 4 + e] = (f16)(xs[e] - (float)hh);
        }
      }
      const int ck = 2 * ua + half;
      *(f16x8*)(row + ((ck ^ rx) * 8)) = h;
      *(f16x8*)(row + (((ck + 4) ^ rx) * 8)) = l;
    }
  };
  auto WRITEB = [&](int buf) {
    f16* row = &Bs[buf][rb][0];
    const int rx = rb & 7;
    #pragma unroll
    for (int half = 0; half < 2; ++half) {
      f16x8 h, l;
      #pragma unroll
      for (int q = 0; q < 2; ++q) {
        float4 v = avB[half * 2 + q];
        const float xs[4] = {v.w, v.z, v.y, v.x};   // width-reversed
        #pragma unroll
        for (int e = 0; e < 4; ++e) {
          f16 hh = (f16)xs[e];
          h[q * 4 + e] = hh;
          l[q * 4 + e] = (f16)(xs[e] - (float)hh);
        }
      }
      const int ck = 2 * ub + half;
      *(f16x8*)(row + ((ck ^ rx) * 8)) = h;
      *(f16x8*)(row + (((ck + 4) ^ rx) * 8)) = l;
    }
  };

  const int aro = wr * 64, bro = wc * 64;
  const int S0 = kz * 32;

  // prologue
  LOADA(S0); if (hasB) LOADB(S0);
  WRITEA(0); if (hasB) WRITEB(0);
  __syncthreads();

  int cur = 0;
  for (int s = 0; s < 32; ++s) {
    if (s < 31) { LOADA(S0 + s + 1); if (hasB) LOADB(S0 + s + 1); }
    #pragma unroll
    for (int kk = 0; kk < 2; ++kk) {
      f16x8 ah[2], al[2], bh[2], bl[2];
      const int c0 = kk * 2 + lh;
      #pragma unroll
      for (int mh = 0; mh < 2; ++mh) {
        const int r1 = aro + mh * 32 + lr, rk1 = r1 & 7;
        ah[mh] = *(const f16x8*)(&As[cur][r1][0] + ((c0 ^ rk1) * 8));
        al[mh] = *(const f16x8*)(&As[cur][r1][0] + (((c0 + 4) ^ rk1) * 8));
        const int r2 = bro + mh * 32 + lr, rk2 = r2 & 7;
        bh[mh] = *(const f16x8*)(&Bs[cur][r2][0] + ((c0 ^ rk2) * 8));
        bl[mh] = *(const f16x8*)(&Bs[cur][r2][0] + (((c0 + 4) ^ rk2) * 8));
      }
      #pragma unroll
      for (int mh = 0; mh < 2; ++mh)
        #pragma unroll
        for (int nh = 0; nh < 2; ++nh) {
          acc[mh][nh] = __builtin_amdgcn_mfma_f32_32x32x16_f16(ah[mh], bh[nh], acc[mh][nh], 0, 0, 0);
          acc[mh][nh] = __builtin_amdgcn_mfma_f32_32x32x16_f16(ah[mh], bl[nh], acc[mh][nh], 0, 0, 0);
          acc[mh][nh] = __builtin_amdgcn_mfma_f32_32x32x16_f16(al[mh], bh[nh], acc[mh][nh], 0, 0, 0);
        }
    }
    if (s < 31) { WRITEA(cur ^ 1); if (hasB) WRITEB(cur ^ 1); }
    __syncthreads();
    cur ^= 1;
  }

  // ---- fold 64x64 pair tile into corr[y], y = (hs - hg) mod 64 ----
  ((float*)corr_s)[tid] = 0.f;
  __syncthreads();
  const int p = wr * 2 + wc;
  #pragma unroll
  for (int r = 0; r < 16; ++r) {
    const int rowof = (r & 3) + 8 * (r >> 2);
    const int y0 = (rowof + 4 * lh - lr) & 63;
    const int y1 = (y0 + 32) & 63;
    atomicAdd(&corr_s[p][y0], acc[0][0][r] + acc[1][1][r]);
    atomicAdd(&corr_s[p][y1], acc[0][1][r] + acc[1][0][r]);
  }
  __syncthreads();
  {
    const int pp = tid >> 6, y = tid & 63;
    const int ip = ipg * 4 + (pp >> 1), jp = jpg * 2 + (pp & 1);
    atomicAdd(&ws[WS_CORR + ((size_t)ip * 32 + jp) * 64 + y], corr_s[pp][y]);
  }
}

// ---------------- argmax over corr -> orien ----------------
__global__ __launch_bounds__(256) void argmax_kernel(const float* __restrict__ ws,
                                                     float* __restrict__ out,
                                                     int* __restrict__ orien) {
  int p = blockIdx.x * 256 + threadIdx.x;
  if (p >= 1024) return;
  const float* c = ws + WS_CORR + (size_t)p * 64;
  float best = c[0];
  int by = 0;
  for (int y = 1; y < 64; ++y) {
    float v = c[y];
    if (v > best) { best = v; by = y; }
  }
  orien[p] = by;
  out[ORIEN_OFF + p] = (float)by;
}

// ---------------- per-pair width-shifted dot (8i x 8j x 16 k-slices) ----------------
__global__ __launch_bounds__(512) void dot3_kernel(const float* __restrict__ sat,
                                                   const float* __restrict__ grd,
                                                   const int* __restrict__ orien,
                                                   float* __restrict__ dots) {
  const int bi = blockIdx.x;   // 0..3 -> 8 i's
  const int bj = blockIdx.y;   // 0..3 -> 8 j's
  const int bz = blockIdx.z;   // 0..15 -> 256 k-rows
  const int tid = threadIdx.x, lane = tid & 63, wvj = tid >> 6;
  const int j = bj * 8 + wvj;
  const int r0 = bz * 256;
  const int i0 = bi * 8;
  const float* gp = grd + (size_t)j * PER_I + (size_t)r0 * 64 + lane;
  const float* sp[8];
  #pragma unroll
  for (int q = 0; q < 8; ++q)
    sp[q] = sat + (size_t)(i0 + q) * PER_I + (size_t)r0 * 64
                + ((lane + orien[(i0 + q) * 32 + j]) & 63);
  float a[8] = {0.f, 0.f, 0.f, 0.f, 0.f, 0.f, 0.f, 0.f};
  #pragma unroll 2
  for (int r = 0; r < 256; ++r) {
    float g = gp[(size_t)r * 64];
    #pragma unroll
    for (int q = 0; q < 8; ++q) a[q] = fmaf(sp[q][(size_t)r * 64], g, a[q]);
  }
  #pragma unroll
  for (int q = 0; q < 8; ++q) {
    float s = a[q];
    for (int off = 32; off; off >>= 1) s += __shfl_down(s, off, 64);
    if (lane == 0) atomicAdd(&dots[(i0 + q) * 32 + j], s);
  }
}

// ---------------- finalize distance ----------------
__global__ __launch_bounds__(256) void finalize_kernel(const float* __restrict__ ws,
                                                       float* __restrict__ out) {
  int t = blockIdx.x * 256 + threadIdx.x;
  if (t >= 1024) return;
  int jj = t >> 5, ii = t & 31;
  float dot = ws[WS_DOTS + ii * 32 + jj] / ws[WS_NORMS + ii];
  out[DIST_OFF + jj * 32 + ii] = 2.f - 2.f * dot;
}

extern "C" void kernel_launch(void* const* d_in, const int* in_sizes, int n_in,
                              void* d_out, int out_size, void* d_ws, size_t ws_size,
                              hipStream_t stream) {
  const float* sat = (const float*)d_in[0];
  const float* grd = (const float*)d_in[1];
  float* out = (float*)d_out;
  float* wsf = (float*)d_ws;

  zero_kernel<<<260, 256, 0, stream>>>(wsf);
  copy_kernel<<<2048, 256, 0, stream>>>((const float4*)sat, (const float4*)grd, (float4*)out);
  norm_kernel<<<32, 256, 0, stream>>>((const float4*)sat, wsf + WS_NORMS);
  gram3_kernel<<<512, 512, 0, stream>>>(sat, grd, wsf);
  argmax_kernel<<<4, 256, 0, stream>>>(wsf, out, (int*)(wsf + WS_ORIEN));
  dot3_kernel<<<dim3(4, 4, 16), 512, 0, stream>>>(sat, grd, (const int*)(wsf + WS_ORIEN), wsf + WS_DOTS);
  finalize_kernel<<<4, 256, 0, stream>>>(wsf, out);
}

// Round 5
// 404.211 us; speedup vs baseline: 2.1883x; 1.0141x over previous
//
#include <hip/hip_runtime.h>
#include <stdint.h>

typedef _Float16 f16;
typedef _Float16 f16x8 __attribute__((ext_vector_type(8)));
typedef float f32x16 __attribute__((ext_vector_type(16)));

#define SAT_ELEMS (32*64*64*64)
#define PER_I (64*64*64)
#define DIST_OFF (2*SAT_ELEMS)
#define ORIEN_OFF (DIST_OFF + 32*32)

// small ws region (float units)
#define WS_NORMS 0          // float[32]
#define WS_ORIEN 64         // int[1024]
#define WS_CORR  2048       // float[1024*64]
#define WS_DOTS  67584      // float[1024]
// big ws region (byte offsets)
#define WSB_SATH (1u<<20)
#define WSB_SATL (WSB_SATH + (uint32_t)SAT_ELEMS*2u)
#define WSB_GRDH (WSB_SATL + (uint32_t)SAT_ELEMS*2u)
#define WSB_GRDL (WSB_GRDH + (uint32_t)SAT_ELEMS*2u)
#define WS_NEED  ((size_t)WSB_GRDL + (size_t)SAT_ELEMS*2u + 1024u)

__device__ __forceinline__ void gll16(const void* src, void* dst) {
  __builtin_amdgcn_global_load_lds(
      (const __attribute__((address_space(1))) uint32_t*)src,
      (__attribute__((address_space(3))) uint32_t*)dst, 16, 0, 0);
}

// ---------------- zero corr+dots scratch ----------------
__global__ __launch_bounds__(256) void zero_kernel(float* __restrict__ ws) {
  int t = blockIdx.x * 256 + threadIdx.x;
  if (t < 65536 + 1024) ws[WS_CORR + t] = 0.f;
}

// ---------------- copy inputs to outputs 0/1 ----------------
__global__ __launch_bounds__(256) void copy_kernel(const float4* __restrict__ sat,
                                                   const float4* __restrict__ grd,
                                                   float4* __restrict__ out) {
  const int n4 = SAT_ELEMS / 4;
  int idx = blockIdx.x * 256 + threadIdx.x;
  int stride = gridDim.x * 256;
  for (int t = idx; t < n4; t += stride) out[t] = sat[t];
  for (int t = idx; t < n4; t += stride) out[n4 + t] = grd[t];
}

// ---------------- per-i norms ----------------
__global__ __launch_bounds__(256) void norm_kernel(const float4* __restrict__ sat,
                                                   float* __restrict__ norms) {
  int i = blockIdx.x;
  const float4* p = sat + (size_t)i * (PER_I / 4);
  float s = 0.f;
  for (int t = threadIdx.x; t < PER_I / 4; t += 256) {
    float4 v = p[t];
    s += v.x * v.x + v.y * v.y + v.z * v.z + v.w * v.w;
  }
  for (int off = 32; off; off >>= 1) s += __shfl_down(s, off, 64);
  __shared__ float red[4];
  int lane = threadIdx.x & 63, wv = threadIdx.x >> 6;
  if (lane == 0) red[wv] = s;
  __syncthreads();
  if (threadIdx.x == 0) norms[i] = sqrtf(red[0] + red[1] + red[2] + red[3] + 1e-8f);
}

// ---------------- precompute f16 hi/lo arrays (grd width-reversed) ----------------
__global__ __launch_bounds__(256) void split_kernel(const float* __restrict__ sat,
                                                    const float* __restrict__ grd,
                                                    uint8_t* __restrict__ wsb) {
  f16* satH = (f16*)(wsb + WSB_SATH);
  f16* satL = (f16*)(wsb + WSB_SATL);
  f16* grdH = (f16*)(wsb + WSB_GRDH);
  f16* grdL = (f16*)(wsb + WSB_GRDL);
  const int NG = SAT_ELEMS / 8;
  int idx = blockIdx.x * 256 + threadIdx.x;
  int stride = gridDim.x * 256;
  for (int g = idx; g < NG; g += stride) {
    {
      float4 f0 = *(const float4*)(sat + (size_t)g * 8);
      float4 f1 = *(const float4*)(sat + (size_t)g * 8 + 4);
      const float xs[8] = {f0.x, f0.y, f0.z, f0.w, f1.x, f1.y, f1.z, f1.w};
      f16x8 h, l;
      #pragma unroll
      for (int e = 0; e < 8; ++e) {
        f16 hh = (f16)xs[e];
        h[e] = hh;
        l[e] = (f16)(xs[e] - (float)hh);
      }
      *(f16x8*)(satH + (size_t)g * 8) = h;
      *(f16x8*)(satL + (size_t)g * 8) = l;
    }
    {
      // grd: out[row][w'] = in[row][63-w'], chunk of 8 at w' = 8t..8t+7
      int rowg = g >> 3, t = g & 7;
      const float* gsrc = grd + (size_t)rowg * 64 + (56 - 8 * t);
      float4 g0 = *(const float4*)(gsrc);
      float4 g1 = *(const float4*)(gsrc + 4);
      const float ys[8] = {g1.w, g1.z, g1.y, g1.x, g0.w, g0.z, g0.y, g0.x};
      f16x8 h, l;
      #pragma unroll
      for (int e = 0; e < 8; ++e) {
        f16 hh = (f16)ys[e];
        h[e] = hh;
        l[e] = (f16)(ys[e] - (float)hh);
      }
      *(f16x8*)(grdH + (size_t)g * 8) = h;
      *(f16x8*)(grdL + (size_t)g * 8) = l;
    }
  }
}

// ---------------- MFMA Gram v4: global_load_lds staging of f16 hi/lo ----------------
// tile 128x128 (2 i's x 2 j's), 4 waves (wave = one pair's 64x64), kz=2 (K=2048, 64 stages).
// LDS row = 64 f16 = 128B = 8x16B chunks: 0-3 hi(k0..31), 4-7 lo; phys slot = ck ^ (row&7).
// DMA writes LDS linearly; source addresses carry the swizzle (rule: both-sides-or-neither).
__global__ __launch_bounds__(256, 2) void gram4_kernel(const uint8_t* __restrict__ wsb,
                                                       float* __restrict__ ws) {
  __shared__ f16 As[2][128][64];   // 32KB
  __shared__ f16 Bs[2][128][64];   // 32KB
  __shared__ float corr_s[4][64];  // 1KB

  const int bid = blockIdx.x;               // 512 blocks
  const int wg = (bid & 7) * 64 + (bid >> 3);  // XCD-chunked swizzle (512%8==0, bijective)
  const int ipg = wg >> 5;                  // 0..15 (2 i's)
  const int rem = wg & 31;
  const int jpg = rem >> 1;                 // 0..15 (2 j's)
  const int kz = rem & 1;                   // K-slice of 2048

  const int tid = threadIdx.x, lane = tid & 63, wv = tid >> 6;
  const int wr = wv >> 1, wc = wv & 1;
  const int lr = lane & 31, lh = lane >> 5;

  // per-lane source byte-offsets for this wave's 4 A-chunks + 4 B-chunks.
  // chunk cc covers LDS rows [8cc, 8cc+8); lane -> row = 8cc + (lane>>3), phys slot pc = lane&7.
  // content at (row, pc) must be logical chunk ck = pc ^ (row&7) = (lane&7)^(lane>>3).
  const int rsub = lane >> 3;
  const int ck = (lane & 7) ^ rsub;
  uint32_t aoff[4], boff[4];
  #pragma unroll
  for (int q = 0; q < 4; ++q) {
    const int cc = wv * 4 + q;
    const int row = cc * 8 + rsub;          // 0..127
    const int h = row & 63, sub = row >> 6;
    const uint32_t lanepart = 2u * ((uint32_t)h * 64u + (uint32_t)(ck & 3) * 8u);
    aoff[q] = (ck < 4 ? WSB_SATH : WSB_SATL)
            + 2u * (uint32_t)(ipg * 2 + sub) * (uint32_t)PER_I + lanepart;
    boff[q] = (ck < 4 ? WSB_GRDH : WSB_GRDL)
            + 2u * (uint32_t)(jpg * 2 + sub) * (uint32_t)PER_I + lanepart;
  }

  f32x16 acc[2][2];
  #pragma unroll
  for (int mh = 0; mh < 2; ++mh)
    #pragma unroll
    for (int nh = 0; nh < 2; ++nh)
      #pragma unroll
      for (int q = 0; q < 16; ++q) acc[mh][nh][q] = 0.f;

  auto ISSUE = [&](int s, int buf) {
    const int k0 = kz * 2048 + s * 32;
    const uint32_t so = 2u * ((uint32_t)(k0 >> 6) * 4096u + (uint32_t)(k0 & 63));
    #pragma unroll
    for (int q = 0; q < 4; ++q) {
      const int cc = wv * 4 + q;
      gll16(wsb + aoff[q] + so, &As[buf][cc * 8][0]);
      gll16(wsb + boff[q] + so, &Bs[buf][cc * 8][0]);
    }
  };

  ISSUE(0, 0);
  __syncthreads();

  int cur = 0;
  for (int s = 0; s < 64; ++s) {
    if (s < 63) ISSUE(s + 1, cur ^ 1);
    #pragma unroll
    for (int kk = 0; kk < 2; ++kk) {
      f16x8 ah[2], al[2], bh[2], bl[2];
      const int c0 = kk * 2 + lh;
      #pragma unroll
      for (int mh = 0; mh < 2; ++mh) {
        const int r1 = wr * 64 + mh * 32 + lr, rk1 = r1 & 7;
        ah[mh] = *(const f16x8*)(&As[cur][r1][0] + ((c0 ^ rk1) * 8));
        al[mh] = *(const f16x8*)(&As[cur][r1][0] + (((c0 + 4) ^ rk1) * 8));
        const int r2 = wc * 64 + mh * 32 + lr, rk2 = r2 & 7;
        bh[mh] = *(const f16x8*)(&Bs[cur][r2][0] + ((c0 ^ rk2) * 8));
        bl[mh] = *(const f16x8*)(&Bs[cur][r2][0] + (((c0 + 4) ^ rk2) * 8));
      }
      #pragma unroll
      for (int mh = 0; mh < 2; ++mh)
        #pragma unroll
        for (int nh = 0; nh < 2; ++nh) {
          acc[mh][nh] = __builtin_amdgcn_mfma_f32_32x32x16_f16(ah[mh], bh[nh], acc[mh][nh], 0, 0, 0);
          acc[mh][nh] = __builtin_amdgcn_mfma_f32_32x32x16_f16(ah[mh], bl[nh], acc[mh][nh], 0, 0, 0);
          acc[mh][nh] = __builtin_amdgcn_mfma_f32_32x32x16_f16(al[mh], bh[nh], acc[mh][nh], 0, 0, 0);
        }
    }
    __syncthreads();
    cur ^= 1;
  }

  // ---- fold 64x64 pair tile into corr[y], y = (hs - hg) mod 64 ----
  if (tid < 256) ((float*)corr_s)[tid] = 0.f;
  __syncthreads();
  #pragma unroll
  for (int r = 0; r < 16; ++r) {
    const int rowof = (r & 3) + 8 * (r >> 2);
    const int y0 = (rowof + 4 * lh - lr) & 63;
    const int y1 = (y0 + 32) & 63;
    atomicAdd(&corr_s[wv][y0], acc[0][0][r] + acc[1][1][r]);
    atomicAdd(&corr_s[wv][y1], acc[0][1][r] + acc[1][0][r]);
  }
  __syncthreads();
  {
    const int pp = tid >> 6, y = tid & 63;
    const int ip = ipg * 2 + (pp >> 1), jp = jpg * 2 + (pp & 1);
    atomicAdd(&ws[WS_CORR + ((size_t)ip * 32 + jp) * 64 + y], corr_s[pp][y]);
  }
}

// ---------------- argmax over corr -> orien ----------------
__global__ __launch_bounds__(256) void argmax_kernel(const float* __restrict__ ws,
                                                     float* __restrict__ out,
                                                     int* __restrict__ orien) {
  int p = blockIdx.x * 256 + threadIdx.x;
  if (p >= 1024) return;
  const float* c = ws + WS_CORR + (size_t)p * 64;
  float best = c[0];
  int by = 0;
  for (int y = 1; y < 64; ++y) {
    float v = c[y];
    if (v > best) { best = v; by = y; }
  }
  orien[p] = by;
  out[ORIEN_OFF + p] = (float)by;
}

// ---------------- per-pair width-shifted dot from f16 arrays ----------------
__global__ __launch_bounds__(512) void dot4_kernel(const uint8_t* __restrict__ wsb,
                                                   const int* __restrict__ orien,
                                                   float* __restrict__ dots) {
  const f16* satH = (const f16*)(wsb + WSB_SATH);
  const f16* grdH = (const f16*)(wsb + WSB_GRDH);  // width-reversed: grd[..][w] = grdH[..][63-w]
  const int bi = blockIdx.x;   // 0..3 -> 8 i's
  const int bj = blockIdx.y;   // 0..3 -> 8 j's
  const int bz = blockIdx.z;   // 0..15 -> 256 k-rows
  const int tid = threadIdx.x, lane = tid & 63, wvj = tid >> 6;
  const int j = bj * 8 + wvj;
  const int r0 = bz * 256;
  const int i0 = bi * 8;
  const f16* gp = grdH + (size_t)j * PER_I + (size_t)r0 * 64 + (63 - lane);
  const f16* sp[8];
  #pragma unroll
  for (int q = 0; q < 8; ++q)
    sp[q] = satH + (size_t)(i0 + q) * PER_I + (size_t)r0 * 64
                 + ((lane + orien[(i0 + q) * 32 + j]) & 63);
  float a[8] = {0.f, 0.f, 0.f, 0.f, 0.f, 0.f, 0.f, 0.f};
  #pragma unroll 2
  for (int r = 0; r < 256; ++r) {
    float g = (float)gp[(size_t)r * 64];
    #pragma unroll
    for (int q = 0; q < 8; ++q) a[q] = fmaf((float)sp[q][(size_t)r * 64], g, a[q]);
  }
  #pragma unroll
  for (int q = 0; q < 8; ++q) {
    float s = a[q];
    for (int off = 32; off; off >>= 1) s += __shfl_down(s, off, 64);
    if (lane == 0) atomicAdd(&dots[(i0 + q) * 32 + j], s);
  }
}

// ---------------- finalize distance ----------------
__global__ __launch_bounds__(256) void finalize_kernel(const float* __restrict__ ws,
                                                       float* __restrict__ out) {
  int t = blockIdx.x * 256 + threadIdx.x;
  if (t >= 1024) return;
  int jj = t >> 5, ii = t & 31;
  float dot = ws[WS_DOTS + ii * 32 + jj] / ws[WS_NORMS + ii];
  out[DIST_OFF + jj * 32 + ii] = 2.f - 2.f * dot;
}

// ================= fallback path (proven round-4 kernels) =================
__global__ __launch_bounds__(512) void gram3_kernel(const float* __restrict__ sat,
                                                    const float* __restrict__ grd,
                                                    float* __restrict__ ws) {
  __shared__ f16 As[2][256][64];
  __shared__ f16 Bs[2][128][64];
  __shared__ float corr_s[8][64];
  const int bid = blockIdx.x;
  const int ipg = bid & 7;
  const int rem = bid >> 3;
  const int jpg = rem >> 2;
  const int kz  = rem & 3;
  const int tid = threadIdx.x;
  const int lane = tid & 63;
  const int wv = tid >> 6;
  const int wr = wv >> 1, wc = wv & 1;
  const int lr = lane & 31, lh = lane >> 5;
  const int ra = tid >> 1, ua = tid & 1;
  const int ia = ipg * 4 + (ra >> 6), ha = ra & 63;
  const bool hasB = (tid < 256);
  const int rb = (tid >> 1) & 127, ub = tid & 1;
  const int jb = jpg * 2 + (rb >> 6), hb = rb & 63;
  const float* abase = sat + (size_t)ia * PER_I + (size_t)ha * 64;
  const float* bbase = grd + (size_t)jb * PER_I + (size_t)hb * 64;
  f32x16 acc[2][2];
  #pragma unroll
  for (int mh = 0; mh < 2; ++mh)
    #pragma unroll
    for (int nh = 0; nh < 2; ++nh)
      #pragma unroll
      for (int q = 0; q < 16; ++q) acc[mh][nh][q] = 0.f;
  float4 avA[4], avB[4];
  auto LOADA = [&](int S) {
    const int c = S >> 1, w0 = (S & 1) * 32;
    const float* p = abase + (size_t)c * 4096 + w0 + ua * 16;
    #pragma unroll
    for (int q = 0; q < 4; ++q) avA[q] = *(const float4*)(p + q * 4);
  };
  auto LOADB = [&](int S) {
    const int c = S >> 1, w0 = (S & 1) * 32;
    const float* p = bbase + (size_t)c * 4096;
    #pragma unroll
    for (int q = 0; q < 4; ++q) avB[q] = *(const float4*)(p + 60 - w0 - ub * 16 - q * 4);
  };
  auto WRITEA = [&](int buf) {
    f16* row = &As[buf][ra][0];
    const int rx = ra & 7;
    #pragma unroll
    for (int half = 0; half < 2; ++half) {
      f16x8 h, l;
      #pragma unroll
      for (int q = 0; q < 2; ++q) {
        float4 v = avA[half * 2 + q];
        const float xs[4] = {v.x, v.y, v.z, v.w};
        #pragma unroll
        for (int e = 0; e < 4; ++e) {
          f16 hh = (f16)xs[e];
          h[q * 4 + e] = hh;
          l[q * 4 + e] = (f16)(xs[e] - (float)hh);
        }
      }
      const int ckk = 2 * ua + half;
      *(f16x8*)(row + ((ckk ^ rx) * 8)) = h;
      *(f16x8*)(row + (((ckk + 4) ^ rx) * 8)) = l;
    }
  };
  auto WRITEB = [&](int buf) {
    f16* row = &Bs[buf][rb][0];
    const int rx = rb & 7;
    #pragma unroll
    for (int half = 0; half < 2; ++half) {
      f16x8 h, l;
      #pragma unroll
      for (int q = 0; q < 2; ++q) {
        float4 v = avB[half * 2 + q];
        const float xs[4] = {v.w, v.z, v.y, v.x};
        #pragma unroll
        for (int e = 0; e < 4; ++e) {
          f16 hh = (f16)xs[e];
          h[q * 4 + e] = hh;
          l[q * 4 + e] = (f16)(xs[e] - (float)hh);
        }
      }
      const int ckk = 2 * ub + half;
      *(f16x8*)(row + ((ckk ^ rx) * 8)) = h;
      *(f16x8*)(row + (((ckk + 4) ^ rx) * 8)) = l;
    }
  };
  const int aro = wr * 64, bro = wc * 64;
  const int S0 = kz * 32;
  LOADA(S0); if (hasB) LOADB(S0);
  WRITEA(0); if (hasB) WRITEB(0);
  __syncthreads();
  int cur = 0;
  for (int s = 0; s < 32; ++s) {
    if (s < 31) { LOADA(S0 + s + 1); if (hasB) LOADB(S0 + s + 1); }
    #pragma unroll
    for (int kk = 0; kk < 2; ++kk) {
      f16x8 ah[2], al[2], bh[2], bl[2];
      const int c0 = kk * 2 + lh;
      #pragma unroll
      for (int mh = 0; mh < 2; ++mh) {
        const int r1 = aro + mh * 32 + lr, rk1 = r1 & 7;
        ah[mh] = *(const f16x8*)(&As[cur][r1][0] + ((c0 ^ rk1) * 8));
        al[mh] = *(const f16x8*)(&As[cur][r1][0] + (((c0 + 4) ^ rk1) * 8));
        const int r2 = bro + mh * 32 + lr, rk2 = r2 & 7;
        bh[mh] = *(const f16x8*)(&Bs[cur][r2][0] + ((c0 ^ rk2) * 8));
        bl[mh] = *(const f16x8*)(&Bs[cur][r2][0] + (((c0 + 4) ^ rk2) * 8));
      }
      #pragma unroll
      for (int mh = 0; mh < 2; ++mh)
        #pragma unroll
        for (int nh = 0; nh < 2; ++nh) {
          acc[mh][nh] = __builtin_amdgcn_mfma_f32_32x32x16_f16(ah[mh], bh[nh], acc[mh][nh], 0, 0, 0);
          acc[mh][nh] = __builtin_amdgcn_mfma_f32_32x32x16_f16(ah[mh], bl[nh], acc[mh][nh], 0, 0, 0);
          acc[mh][nh] = __builtin_amdgcn_mfma_f32_32x32x16_f16(al[mh], bh[nh], acc[mh][nh], 0, 0, 0);
        }
    }
    if (s < 31) { WRITEA(cur ^ 1); if (hasB) WRITEB(cur ^ 1); }
    __syncthreads();
    cur ^= 1;
  }
  ((float*)corr_s)[tid] = 0.f;
  __syncthreads();
  const int p = wr * 2 + wc;
  #pragma unroll
  for (int r = 0; r < 16; ++r) {
    const int rowof = (r & 3) + 8 * (r >> 2);
    const int y0 = (rowof + 4 * lh - lr) & 63;
    const int y1 = (y0 + 32) & 63;
    atomicAdd(&corr_s[p][y0], acc[0][0][r] + acc[1][1][r]);
    atomicAdd(&corr_s[p][y1], acc[0][1][r] + acc[1][0][r]);
  }
  __syncthreads();
  {
    const int pp = tid >> 6, y = tid & 63;
    const int ip = ipg * 4 + (pp >> 1), jp = jpg * 2 + (pp & 1);
    atomicAdd(&ws[WS_CORR + ((size_t)ip * 32 + jp) * 64 + y], corr_s[pp][y]);
  }
}

__global__ __launch_bounds__(512) void dot3_kernel(const float* __restrict__ sat,
                                                   const float* __restrict__ grd,
                                                   const int* __restrict__ orien,
                                                   float* __restrict__ dots) {
  const int bi = blockIdx.x;
  const int bj = blockIdx.y;
  const int bz = blockIdx.z;
  const int tid = threadIdx.x, lane = tid & 63, wvj = tid >> 6;
  const int j = bj * 8 + wvj;
  const int r0 = bz * 256;
  const int i0 = bi * 8;
  const float* gp = grd + (size_t)j * PER_I + (size_t)r0 * 64 + lane;
  const float* sp[8];
  #pragma unroll
  for (int q = 0; q < 8; ++q)
    sp[q] = sat + (size_t)(i0 + q) * PER_I + (size_t)r0 * 64
                + ((lane + orien[(i0 + q) * 32 + j]) & 63);
  float a[8] = {0.f, 0.f, 0.f, 0.f, 0.f, 0.f, 0.f, 0.f};
  #pragma unroll 2
  for (int r = 0; r < 256; ++r) {
    float g = gp[(size_t)r * 64];
    #pragma unroll
    for (int q = 0; q < 8; ++q) a[q] = fmaf(sp[q][(size_t)r * 64], g, a[q]);
  }
  #pragma unroll
  for (int q = 0; q < 8; ++q) {
    float s = a[q];
    for (int off = 32; off; off >>= 1) s += __shfl_down(s, off, 64);
    if (lane == 0) atomicAdd(&dots[(i0 + q) * 32 + j], s);
  }
}

extern "C" void kernel_launch(void* const* d_in, const int* in_sizes, int n_in,
                              void* d_out, int out_size, void* d_ws, size_t ws_size,
                              hipStream_t stream) {
  const float* sat = (const float*)d_in[0];
  const float* grd = (const float*)d_in[1];
  float* out = (float*)d_out;
  float* wsf = (float*)d_ws;
  uint8_t* wsb = (uint8_t*)d_ws;

  zero_kernel<<<260, 256, 0, stream>>>(wsf);
  copy_kernel<<<2048, 256, 0, stream>>>((const float4*)sat, (const float4*)grd, (float4*)out);
  norm_kernel<<<32, 256, 0, stream>>>((const float4*)sat, wsf + WS_NORMS);

  if (ws_size >= WS_NEED) {
    split_kernel<<<2048, 256, 0, stream>>>(sat, grd, wsb);
    gram4_kernel<<<512, 256, 0, stream>>>(wsb, wsf);
    argmax_kernel<<<4, 256, 0, stream>>>(wsf, out, (int*)(wsf + WS_ORIEN));
    dot4_kernel<<<dim3(4, 4, 16), 512, 0, stream>>>(wsb, (const int*)(wsf + WS_ORIEN), wsf + WS_DOTS);
  } else {
    gram3_kernel<<<512, 512, 0, stream>>>(sat, grd, wsf);
    argmax_kernel<<<4, 256, 0, stream>>>(wsf, out, (int*)(wsf + WS_ORIEN));
    dot3_kernel<<<dim3(4, 4, 16), 512, 0, stream>>>(sat, grd, (const int*)(wsf + WS_ORIEN), wsf + WS_DOTS);
  }
  finalize_kernel<<<4, 256, 0, stream>>>(wsf, out);
}